// Round 7
// baseline (138.763 us; speedup 1.0000x reference)
//
#include <hip/hip_runtime.h>
#include <hip/hip_bf16.h>

// Problem constants (from reference)
constexpr int T_ = 4;
constexpr int B_ = 8;
constexpr int N_ = 5000;
constexpr int E_ = 80000;
constexpr int TBN = T_ * B_ * N_;   // 160000
constexpr int NXCD = 8;

// layer-kernel geometry: 4 lanes per node-slot, 64 slots per 256-thread block
constexpr int NPB = 64;                       // slots per block
constexpr int CH  = (N_ + NPB - 1) / NPB;     // 79 chunks per graph
constexpr int GRP = T_ * B_ / NXCD;           // 4 graphs per XCD
constexpr int LB  = NXCD * CH * GRP;          // 2528 blocks

// bf16 pack/unpack (round-to-nearest-ish via +0x8000)
__device__ __forceinline__ unsigned bf16pack2(float lo, float hi) {
    unsigned ul = (__float_as_uint(lo) + 0x8000u) >> 16;
    unsigned uh = (__float_as_uint(hi) + 0x8000u) & 0xffff0000u;
    return uh | ul;
}
__device__ __forceinline__ void bf16unpack2(unsigned u, float& lo, float& hi) {
    lo = __uint_as_float(u << 16);
    hi = __uint_as_float(u & 0xffff0000u);
}

// ---------------------------------------------------------------------------
// Fused CSR prologue, single block: degree (LDS) -> scan -> row_start,
// degree-sorted perm/inv (counting sort), cursor zeroing.
// Slot order within a degree bin is atomic-arbitrary; per-node math is
// placement-invariant, so final output is unchanged.
// ---------------------------------------------------------------------------
__global__ __launch_bounds__(1024) void k_build1(
        const int* __restrict__ edge_dst, int* __restrict__ row_start,
        int* __restrict__ perm, int* __restrict__ inv, int* __restrict__ cursor) {
    __shared__ int sdeg[5120];
    __shared__ int ssum[1024];
    __shared__ int hist[64];
    __shared__ int hbase[64];
    const int tid = threadIdx.x;
    for (int i = tid; i < 5120; i += 1024) sdeg[i] = 0;
    __syncthreads();
    for (int e = tid; e < E_; e += 1024) atomicAdd(&sdeg[edge_dst[e]], 1);
    __syncthreads();
    // exclusive scan, 5 elements per thread
    const int base = tid * 5;
    int loc = 0;
#pragma unroll
    for (int i = 0; i < 5; ++i) { int ix = base + i; if (ix < N_) loc += sdeg[ix]; }
    ssum[tid] = loc;
    __syncthreads();
    for (int off = 1; off < 1024; off <<= 1) {
        int v = 0;
        if (tid >= off) v = ssum[tid - off];
        __syncthreads();
        if (tid >= off) ssum[tid] += v;
        __syncthreads();
    }
    int run = ssum[tid] - loc;
#pragma unroll
    for (int i = 0; i < 5; ++i) {
        int ix = base + i;
        if (ix < N_) { row_start[ix] = run; run += sdeg[ix]; }
    }
    if (tid == 1023) row_start[N_] = ssum[1023];
    for (int i = tid; i < N_; i += 1024) cursor[i] = 0;
    // counting sort by degree (bins 0..63)
    if (tid < 64) hist[tid] = 0;
    __syncthreads();
    for (int i = tid; i < N_; i += 1024) atomicAdd(&hist[min(sdeg[i], 63)], 1);
    __syncthreads();
    if (tid == 0) {
        int r = 0;
        for (int b = 0; b < 64; ++b) { hbase[b] = r; r += hist[b]; }
    }
    __syncthreads();
    if (tid < 64) hist[tid] = 0;
    __syncthreads();
    for (int i = tid; i < N_; i += 1024) {
        int d = min(sdeg[i], 63);
        int p = atomicAdd(&hist[d], 1);
        int slot = hbase[d] + p;
        perm[slot] = i;
        inv[i] = slot;
    }
}

// scatter edges into CSR, translating src node-ids to slot-ids
__global__ void k_build2(const int* __restrict__ src, const int* __restrict__ dst,
                         const int* __restrict__ row_start, int* __restrict__ cursor,
                         const int* __restrict__ inv, int* __restrict__ csr_srcT) {
    int e = blockIdx.x * 256 + threadIdx.x;
    if (e < E_) {
        int d = dst[e];
        int pos = atomicAdd(&cursor[d], 1);
        csr_srcT[row_start[d] + pos] = inv[src[e]];
    }
}

// ---------------------------------------------------------------------------
// Slot-major init: xs4 / vec / charges permuted into degree-sorted slot order
// (one-time scattered reads, coalesced writes).
// ---------------------------------------------------------------------------
__global__ void k_init(const float* __restrict__ xs, const float* __restrict__ vs,
                       const float* __restrict__ charges, const int* __restrict__ perm,
                       float4* __restrict__ xs4, float* __restrict__ vec,
                       float* __restrict__ chs) {
    int g = blockIdx.x * 256 + threadIdx.x;   // 625*256 == TBN exact
    int tb = g / N_;
    int i  = g - tb * N_;
    int node = perm[i];
    size_t sn = (size_t)tb * N_ + node;
    xs4[g] = make_float4(xs[3*sn], xs[3*sn+1], xs[3*sn+2], 0.0f);
    vec[3*(size_t)g+0] = vs[3*sn+0];
    vec[3*(size_t)g+1] = vs[3*sn+1];
    vec[3*(size_t)g+2] = vs[3*sn+2];
    if (tb < B_) chs[g] = charges[sn];
}

// ---------------------------------------------------------------------------
// Fused layer kernel, slot-major state. 4 lanes/slot, edges striped across
// the quad, depth-2 software-pipelined gathers (round-5 structure).
// State: h fp32[TBN][16] (own quarter), gs/gd bf16[TBN][16], all slot-major.
// LYR==0: gs0[s]=c_s*P, gd0=c_n*Q+b1 inline; per-edge gather = charge (4B).
// HAS_NEXT tail feature-split across quad (hnew quarter -> shfl -> proj).
// Only row_start/perm are node-space (3 scalar loads per thread, once).
// ---------------------------------------------------------------------------
template <int LYR, bool HAS_NEXT>
__global__ __launch_bounds__(256, 4) void k_layer(
        const float4* __restrict__ xs4, const float* __restrict__ chs,
        const float* __restrict__ W_embed,
        const float* __restrict__ W1, const float* __restrict__ b1,
        const float* __restrict__ W2, const float* __restrict__ b2,
        const float* __restrict__ Wv,
        const int* __restrict__ row_start, const int* __restrict__ csr_srcT,
        const int* __restrict__ perm,
        float* __restrict__ h, const uint4* __restrict__ gs_in,
        uint2* __restrict__ gs_out, unsigned* __restrict__ gd,
        float* __restrict__ vec) {
    __shared__ float s_w1e[16], s_wv[16], s_b2[16], s_b1[16], s_b1n[16];
    __shared__ float s_W2[256];
    __shared__ float s_W1sn[256];          // next layer rows 0..15
    __shared__ float s_W1dn[256];          // next layer rows 16..31
    __shared__ float s_P[16], s_Q[16], s_rwe[16];   // layer-0 collapse
    const int tid = threadIdx.x;
    if (tid < 16) {
        s_w1e[tid] = W1[LYR * 528 + 512 + tid];
        s_wv[tid]  = Wv[LYR * 16 + tid];
        s_b2[tid]  = b2[LYR * 16 + tid];
        s_b1[tid]  = b1[LYR * 16 + tid];
        if (HAS_NEXT) s_b1n[tid] = b1[(LYR + 1) * 16 + tid];
    }
    s_W2[tid] = W2[LYR * 256 + tid];
    if (HAS_NEXT) {
        s_W1sn[tid] = W1[(LYR + 1) * 528 + tid];
        s_W1dn[tid] = W1[(LYR + 1) * 528 + 256 + tid];
    }
    if (LYR == 0 && tid < 16) {
        float accP = 0.0f, accQ = 0.0f;
        for (int j = 0; j < 16; ++j) {
            float r = fmaxf(W_embed[j], 0.0f);
            accP += r * W1[j * 16 + tid];          // W1s layer0
            accQ += r * W1[256 + j * 16 + tid];    // W1d layer0
        }
        s_P[tid] = accP; s_Q[tid] = accQ;
        s_rwe[tid] = fmaxf(W_embed[tid], 0.0f);
    }
    __syncthreads();

    // XCD swizzle bijection over 2528 = 8 * 316 blocks
    const int bid   = blockIdx.x;
    const int xcd   = bid & 7;
    const int j     = bid >> 3;            // 0..315
    const int tb    = xcd + NXCD * (j / CH);
    const int chunk = j % CH;
    const int slot  = chunk * NPB + (tid >> 2);
    const int q     = tid & 3;
    if (slot >= N_) return;                // whole quad exits together; no syncs below

    const int g = tb * N_ + slot;          // slot-major own index (coalesced)
    const size_t nb = (size_t)tb * N_;
    const float* cb = chs + (tb % B_) * N_;

    const float4 xn = xs4[g];

    // gdn: full 16, per lane (own-index, coalesced)
    float gdn[16];
    float c0 = 0.0f;
    if (LYR == 0) {
        c0 = cb[slot];
#pragma unroll
        for (int f = 0; f < 16; ++f) gdn[f] = c0 * s_Q[f] + s_b1[f];
    } else {
        const uint4* gdp = (const uint4*)gd + (size_t)g * 2;
        uint4 da = gdp[0], db = gdp[1];
        bf16unpack2(da.x, gdn[0], gdn[1]);  bf16unpack2(da.y, gdn[2], gdn[3]);
        bf16unpack2(da.z, gdn[4], gdn[5]);  bf16unpack2(da.w, gdn[6], gdn[7]);
        bf16unpack2(db.x, gdn[8], gdn[9]);  bf16unpack2(db.y, gdn[10], gdn[11]);
        bf16unpack2(db.z, gdn[12], gdn[13]); bf16unpack2(db.w, gdn[14], gdn[15]);
    }

    float agg[16];
#pragma unroll
    for (int f = 0; f < 16; ++f) agg[f] = 0.0f;
    float av0 = 0.0f, av1 = 0.0f, av2 = 0.0f;

    // CSR row lives in node space: 3 scattered scalar loads, once per thread
    const int node = perm[slot];
    const int rs = row_start[node];
    const int re = row_start[node + 1];

    // depth-2 software-pipelined edge loop (edges striped across quad)
    int e = rs + q;
    bool have = e < re;
    int s = have ? csr_srcT[e] : 0;        // slot id of src
    size_t si = nb + (size_t)s;
    float4 xc = xs4[si];
    float  cs = 0.0f;
    uint4  ga, gb;
    if (LYR == 0) cs = cb[s];
    else { ga = gs_in[si * 2]; gb = gs_in[si * 2 + 1]; }

    while (have) {
        int e2 = e + 4;
        bool have2 = e2 < re;
        int s2 = have2 ? csr_srcT[e2] : 0;
        size_t si2 = nb + (size_t)s2;
        float4 xc2 = xs4[si2];
        float  cs2 = 0.0f;
        uint4  ga2, gb2;
        if (LYR == 0) cs2 = cb[s2];
        else { ga2 = gs_in[si2 * 2]; gb2 = gs_in[si2 * 2 + 1]; }

        float d0 = xn.x - xc.x;
        float d1 = xn.y - xc.y;
        float d2v = xn.z - xc.z;
        float dd = d0*d0 + d1*d1 + d2v*d2v;

        float gsf[16];
        if (LYR == 0) {
#pragma unroll
            for (int f = 0; f < 16; ++f) gsf[f] = cs * s_P[f];
        } else {
            bf16unpack2(ga.x, gsf[0], gsf[1]);  bf16unpack2(ga.y, gsf[2], gsf[3]);
            bf16unpack2(ga.z, gsf[4], gsf[5]);  bf16unpack2(ga.w, gsf[6], gsf[7]);
            bf16unpack2(gb.x, gsf[8], gsf[9]);  bf16unpack2(gb.y, gsf[10], gsf[11]);
            bf16unpack2(gb.z, gsf[12], gsf[13]); bf16unpack2(gb.w, gsf[14], gsf[15]);
        }

        float sval = 0.0f;
#pragma unroll
        for (int f = 0; f < 16; ++f) {
            float mv = fmaxf(__builtin_fmaf(dd, s_w1e[f], gdn[f]) + gsf[f], 0.0f);
            if (HAS_NEXT) agg[f] += mv;
            sval = __builtin_fmaf(mv, s_wv[f], sval);
        }
        av0 = __builtin_fmaf(d0, sval, av0);
        av1 = __builtin_fmaf(d1, sval, av1);
        av2 = __builtin_fmaf(d2v, sval, av2);

        e = e2; have = have2; xc = xc2; cs = cs2; ga = ga2; gb = gb2;
    }

    // quad reduce of av (lanes of a quad are consecutive & quad-aligned)
    av0 += __shfl_xor(av0, 1); av0 += __shfl_xor(av0, 2);
    av1 += __shfl_xor(av1, 1); av1 += __shfl_xor(av1, 2);
    av2 += __shfl_xor(av2, 1); av2 += __shfl_xor(av2, 2);

    if (q < 3) {
        float myav = (q == 0) ? av0 : ((q == 1) ? av1 : av2);
        size_t vi = (size_t)g * 3 + q;
        vec[vi] += myav;                   // vec pre-initialized to vs (slot-major)
    }

    if (HAS_NEXT) {
        // full agg across quad (hnew needs all 16 j)
#pragma unroll
        for (int f = 0; f < 16; ++f) {
            agg[f] += __shfl_xor(agg[f], 1);
            agg[f] += __shfl_xor(agg[f], 2);
        }

        // hn quarter for this lane
        float hq[4];
        if (LYR == 0) {
#pragma unroll
            for (int k = 0; k < 4; ++k) hq[k] = c0 * s_rwe[q * 4 + k];
        } else {
            float4 hv = ((const float4*)h)[(size_t)g * 4 + q];
            hq[0] = hv.x; hq[1] = hv.y; hq[2] = hv.z; hq[3] = hv.w;
        }

        // hnew quarter: hq += relu(agg @ W2 + b2) for own 4 features
        float acc[4];
#pragma unroll
        for (int k = 0; k < 4; ++k) acc[k] = s_b2[q * 4 + k];
#pragma unroll
        for (int jj = 0; jj < 16; ++jj) {
            float aj = agg[jj];
#pragma unroll
            for (int k = 0; k < 4; ++k)
                acc[k] = __builtin_fmaf(aj, s_W2[jj * 16 + q * 4 + k], acc[k]);
        }
#pragma unroll
        for (int k = 0; k < 4; ++k) hq[k] += fmaxf(acc[k], 0.0f);

        // exchange quarters -> full hnew
        const int lane = tid & 63;
        const int lbase = lane & ~3;
        float hfull[16];
#pragma unroll
        for (int sq = 0; sq < 4; ++sq) {
#pragma unroll
            for (int k = 0; k < 4; ++k)
                hfull[sq * 4 + k] = __shfl(hq[k], lbase + sq, 64);
        }

        // next-layer projections, own 4 columns
        float gso[4], gdo[4];
#pragma unroll
        for (int k = 0; k < 4; ++k) { gso[k] = 0.0f; gdo[k] = s_b1n[q * 4 + k]; }
#pragma unroll
        for (int jj = 0; jj < 16; ++jj) {
            float hj = hfull[jj];
#pragma unroll
            for (int k = 0; k < 4; ++k) {
                gso[k] = __builtin_fmaf(hj, s_W1sn[jj * 16 + q * 4 + k], gso[k]);
                gdo[k] = __builtin_fmaf(hj, s_W1dn[jj * 16 + q * 4 + k], gdo[k]);
            }
        }

        ((float4*)h)[(size_t)g * 4 + q] = make_float4(hq[0], hq[1], hq[2], hq[3]);
        gs_out[(size_t)g * 4 + q] = make_uint2(bf16pack2(gso[0], gso[1]),
                                               bf16pack2(gso[2], gso[3]));
        ((uint2*)gd)[(size_t)g * 4 + q] = make_uint2(bf16pack2(gdo[0], gdo[1]),
                                                     bf16pack2(gdo[2], gdo[3]));
    }
}

// ---------------------------------------------------------------------------
// Final: out[b*N+n] = sum_t softmax(theta)[t] * (vec_slot[t,b,inv[n]] + xs[t,b,n])
// ---------------------------------------------------------------------------
__global__ void k_final(const float* __restrict__ xs, const float* __restrict__ vec,
                        const float* __restrict__ theta, const int* __restrict__ inv,
                        float* __restrict__ out) {
    int g = blockIdx.x * 256 + threadIdx.x;
    if (g >= B_ * N_) return;
    float t0 = theta[0], t1 = theta[1], t2 = theta[2], t3 = theta[3];
    float mx = fmaxf(fmaxf(t0, t1), fmaxf(t2, t3));
    float e0 = expf(t0 - mx), e1 = expf(t1 - mx), e2 = expf(t2 - mx), e3 = expf(t3 - mx);
    float is = 1.0f / (e0 + e1 + e2 + e3);
    float w[4] = {e0 * is, e1 * is, e2 * is, e3 * is};

    int b = g / N_;
    int n = g - b * N_;
    int slot = inv[n];
    float o0 = 0.0f, o1 = 0.0f, o2 = 0.0f;
#pragma unroll
    for (int t = 0; t < 4; ++t) {
        size_t vi = ((size_t)(t * B_ + b) * N_ + slot) * 3;
        size_t xi = ((size_t)(t * B_ + b) * N_ + n) * 3;
        o0 += w[t] * (vec[vi+0] + xs[xi+0]);
        o1 += w[t] * (vec[vi+1] + xs[xi+1]);
        o2 += w[t] * (vec[vi+2] + xs[xi+2]);
    }
    out[(size_t)g*3+0] = o0;
    out[(size_t)g*3+1] = o1;
    out[(size_t)g*3+2] = o2;
}

// ---------------------------------------------------------------------------
extern "C" void kernel_launch(void* const* d_in, const int* in_sizes, int n_in,
                              void* d_out, int out_size, void* d_ws, size_t ws_size,
                              hipStream_t stream) {
    const float* xs       = (const float*)d_in[0];
    const float* vs       = (const float*)d_in[1];
    const float* charges  = (const float*)d_in[2];
    const int*   edge_src = (const int*)d_in[3];
    const int*   edge_dst = (const int*)d_in[4];
    const float* theta    = (const float*)d_in[5];
    const float* W_embed  = (const float*)d_in[6];
    const float* W1       = (const float*)d_in[7];
    const float* b1       = (const float*)d_in[8];
    const float* W2       = (const float*)d_in[9];
    const float* b2       = (const float*)d_in[10];
    const float* Wv       = (const float*)d_in[11];
    float* out = (float*)d_out;

    // workspace layout (256B aligned)
    char* w = (char*)d_ws;
    size_t off = 0;
    auto take = [&](size_t bytes) {
        size_t o = off;
        off = (off + bytes + 255) & ~(size_t)255;
        return o;
    };
    int*      cursor    = (int*)(w + take((size_t)N_ * 4));
    int*      row_start = (int*)(w + take((size_t)(N_ + 1) * 4));
    int*      csr_srcT  = (int*)(w + take((size_t)E_ * 4));
    int*      perm      = (int*)(w + take((size_t)N_ * 4));
    int*      inv       = (int*)(w + take((size_t)N_ * 4));
    float*    h         = (float*)(w + take((size_t)TBN * 16 * 4));
    unsigned* gsA       = (unsigned*)(w + take((size_t)TBN * 32));   // bf16 x16
    unsigned* gsB       = (unsigned*)(w + take((size_t)TBN * 32));
    unsigned* gd        = (unsigned*)(w + take((size_t)TBN * 32));
    float*    vec       = (float*)(w + take((size_t)TBN * 3 * 4));
    float4*   xs4       = (float4*)(w + take((size_t)TBN * 16));
    float*    chs       = (float*)(w + take((size_t)B_ * N_ * 4));
    (void)ws_size;

    k_build1<<<1, 1024, 0, stream>>>(edge_dst, row_start, perm, inv, cursor);
    const int eb = (E_ + 255) / 256;        // 313
    k_build2<<<eb, 256, 0, stream>>>(edge_src, edge_dst, row_start, cursor, inv, csr_srcT);

    k_init<<<TBN / 256, 256, 0, stream>>>(xs, vs, charges, perm, xs4, vec, chs);

    // layer 0 writes gsA+gd; layer 1 reads gsA writes gsB+gd; layer 2 reads gsB+gd
    k_layer<0, true ><<<LB, 256, 0, stream>>>(xs4, chs, W_embed, W1, b1, W2, b2, Wv,
                                              row_start, csr_srcT, perm, h, nullptr,
                                              (uint2*)gsA, gd, vec);
    k_layer<1, true ><<<LB, 256, 0, stream>>>(xs4, chs, W_embed, W1, b1, W2, b2, Wv,
                                              row_start, csr_srcT, perm, h, (const uint4*)gsA,
                                              (uint2*)gsB, gd, vec);
    k_layer<2, false><<<LB, 256, 0, stream>>>(xs4, chs, W_embed, W1, b1, W2, b2, Wv,
                                              row_start, csr_srcT, perm, h, (const uint4*)gsB,
                                              nullptr, gd, vec);

    const int fb = (B_ * N_ + 255) / 256;   // 157
    k_final<<<fb, 256, 0, stream>>>(xs, vec, theta, inv, out);
}